// Round 3
// baseline (308.235 us; speedup 1.0000x reference)
//
#include <hip/hip_runtime.h>
#include <hip/hip_bf16.h>
#include <stdint.h>

#define N_NODES 50000
#define HALF_N  25000
#define DEG 16
#define IN_F 256
#define HEADS 4
#define OUT_F 64
#define HF 256          // HEADS * OUT_F
#define NEG_SLOPE 0.2f

typedef short bf16x8 __attribute__((ext_vector_type(8)));
typedef float f32x4 __attribute__((ext_vector_type(4)));

__device__ __forceinline__ unsigned short f2b(float f) {
    __hip_bfloat16 b = __float2bfloat16(f);
    return *(unsigned short*)&b;
}
__device__ __forceinline__ float b2f(unsigned short u) {
    union { uint32_t i; float f; } v; v.i = ((uint32_t)u) << 16;
    return v.f;
}

// Kernel 0: pack W [256][256] fp32 into bf16 MFMA-fragment order.
// Chunk G = (cb*8 + kc8)*64 + kg*16 + ar holds W[cb*16+ar][kc8*32+kg*8 .. +8].
// Consumer (proj) then loads bfrag as a fully-contiguous 1KB wave read.
__global__ __launch_bounds__(256) void wprep(
    const float* __restrict__ W, unsigned short* __restrict__ Wbp)
{
    const int G = blockIdx.x * 256 + threadIdx.x;   // 8192 chunks
    const int cb   = G >> 9;          // col-block (16 cols of W^T output)
    const int rem  = G & 511;
    const int kc8  = rem >> 6;        // k-chunk of 32
    const int lane = rem & 63;
    const int kg   = lane >> 4;
    const int ar   = lane & 15;
    const float* src = W + (size_t)(cb * 16 + ar) * IN_F + kc8 * 32 + kg * 8;
    float4 f0 = ((const float4*)src)[0];
    float4 f1 = ((const float4*)src)[1];
    bf16x8 v;
    v[0] = (short)f2b(f0.x); v[1] = (short)f2b(f0.y);
    v[2] = (short)f2b(f0.z); v[3] = (short)f2b(f0.w);
    v[4] = (short)f2b(f1.x); v[5] = (short)f2b(f1.y);
    v[6] = (short)f2b(f1.z); v[7] = (short)f2b(f1.w);
    *(bf16x8*)(Wbp + (size_t)G * 8) = v;
}

// Kernel 1: fused projection GEMM + attention-half reduction.
// Tile 32 rows x 256 cols, 4 waves (wave = head, 64 cols), grid 1563 blocks
// (~6 blocks/CU vs R2's 3 -> occupancy fix). x staged in LDS bf16, swizzled.
__global__ __launch_bounds__(256) void proj_fused(
    const float* __restrict__ x, const unsigned short* __restrict__ Wbp,
    const float* __restrict__ atti, const float* __restrict__ attj,
    unsigned short* __restrict__ h,
    float* __restrict__ a_i, float* __restrict__ a_j)
{
    __shared__ unsigned short As[32 * 256];   // 16 KB

    const int tid  = threadIdx.x;
    const int lane = tid & 63;
    const int wave = tid >> 6;
    const int m0   = blockIdx.x * 32;

    // stage x-tile: 1024 16B-chunks, 4 per thread, coalesced fp32 reads
    #pragma unroll
    for (int p = 0; p < 4; p++) {
        const int C   = p * 256 + tid;
        const int row = C >> 5;
        const int c   = C & 31;
        int grow = m0 + row;
        if (grow >= N_NODES) grow = N_NODES - 1;
        const float* src = x + (size_t)grow * IN_F + c * 8;
        float4 f0 = ((const float4*)src)[0];
        float4 f1 = ((const float4*)src)[1];
        bf16x8 v;
        v[0] = (short)f2b(f0.x); v[1] = (short)f2b(f0.y);
        v[2] = (short)f2b(f0.z); v[3] = (short)f2b(f0.w);
        v[4] = (short)f2b(f1.x); v[5] = (short)f2b(f1.y);
        v[6] = (short)f2b(f1.z); v[7] = (short)f2b(f1.w);
        const int sc = c ^ (row & 7);
        *(bf16x8*)(As + row * 256 + sc * 8) = v;
    }
    __syncthreads();

    const int ar = lane & 15;
    const int kg = lane >> 4;
    const int ncol0 = wave * 64;

    f32x4 acc[2][4];
    #pragma unroll
    for (int i = 0; i < 2; i++)
        #pragma unroll
        for (int j = 0; j < 4; j++)
            #pragma unroll
            for (int k = 0; k < 4; k++) acc[i][j][k] = 0.0f;

    #pragma unroll
    for (int kc8 = 0; kc8 < 8; kc8++) {
        bf16x8 afrag[2], bfrag[4];
        #pragma unroll
        for (int mi = 0; mi < 2; mi++) {
            const int row = mi * 16 + ar;
            const int sc  = (kc8 * 4 + kg) ^ (row & 7);
            afrag[mi] = *(const bf16x8*)(As + row * 256 + sc * 8);
        }
        #pragma unroll
        for (int ni = 0; ni < 4; ni++) {
            const int cb = wave * 4 + ni;
            bfrag[ni] = *(const bf16x8*)(Wbp + ((size_t)(cb * 8 + kc8) * 64 + lane) * 8);
        }
        #pragma unroll
        for (int mi = 0; mi < 2; mi++)
            #pragma unroll
            for (int ni = 0; ni < 4; ni++)
                acc[mi][ni] = __builtin_amdgcn_mfma_f32_16x16x32_bf16(
                    afrag[mi], bfrag[ni], acc[mi][ni], 0, 0, 0);
    }

    // epilogue: h store (bf16) + fused a_i/a_j (fp32-acc precision)
    float ai_l[4], aj_l[4];
    #pragma unroll
    for (int ni = 0; ni < 4; ni++) {
        ai_l[ni] = atti[ncol0 + ni * 16 + ar];
        aj_l[ni] = attj[ncol0 + ni * 16 + ar];
    }
    #pragma unroll
    for (int mi = 0; mi < 2; mi++) {
        #pragma unroll
        for (int reg = 0; reg < 4; reg++) {
            const int row = m0 + mi * 16 + kg * 4 + reg;
            float pi = 0.f, pj = 0.f;
            #pragma unroll
            for (int ni = 0; ni < 4; ni++) {
                const float v = acc[mi][ni][reg];
                pi += v * ai_l[ni];
                pj += v * aj_l[ni];
            }
            #pragma unroll
            for (int off = 1; off < 16; off <<= 1) {
                pi += __shfl_xor(pi, off);
                pj += __shfl_xor(pj, off);
            }
            if (row < N_NODES) {
                #pragma unroll
                for (int ni = 0; ni < 4; ni++)
                    h[(size_t)row * HF + ncol0 + ni * 16 + ar] = f2b(acc[mi][ni][reg]);
                if (ar == 0) {
                    a_i[row * HEADS + wave] = pi;
                    a_j[row * HEADS + wave] = pj;
                }
            }
        }
    }
}

// Kernel 2: softmax + gather-sum, feature-slice (=head) pinned to XCD pair,
// src-range two-phase gather so per-XCD live set = 3.2 MB < 4 MB L2.
// Grid 50000 blocks; wave = one (node, slice); lane = feature within slice.
__global__ __launch_bounds__(256) void gat_agg2(
    const unsigned short* __restrict__ h,
    const float* __restrict__ a_i, const float* __restrict__ a_j,
    const int* __restrict__ col, float* __restrict__ out)
{
    const int bid  = blockIdx.x;
    const int xcd  = bid & 7;                    // dispatch round-robins XCDs
    const int s    = xcd >> 1;                   // slice = head, pinned to XCD pair
    const int nb   = ((bid >> 3) << 1) + (bid & 1);
    const int lane = threadIdx.x & 63;
    const int node = (nb << 2) + (threadIdx.x >> 6);   // exact: 12500*4 = N

    // per-edge logits (replicated across the 4 lane-quads; no divergence)
    const int j16 = lane & 15;
    const int src = __builtin_nontemporal_load(col + node * DEG + j16);
    float e = a_i[node * HEADS + s] + a_j[src * HEADS + s];
    e = (e > 0.0f) ? e : NEG_SLOPE * e;
    float m = e;
    #pragma unroll
    for (int off = 1; off < 16; off <<= 1) m = fmaxf(m, __shfl_xor(m, off));
    float p = __expf(e - m);
    float sum = p;
    #pragma unroll
    for (int off = 1; off < 16; off <<= 1) sum += __shfl_xor(sum, off);
    const float alpha = p / (sum + 1e-16f);

    // two-phase gather: phase 0 -> src < HALF_N, phase 1 -> src >= HALF_N
    float acc = 0.0f;
    #pragma unroll
    for (int phase = 0; phase < 2; phase++) {
        #pragma unroll
        for (int j = 0; j < 16; j++) {
            const int sj = __builtin_amdgcn_readfirstlane(__shfl(src, j));
            if ((int)(sj < HALF_N) != phase) {
                const float al = __shfl(alpha, j);
                acc += al * b2f(h[(size_t)sj * HF + s * OUT_F + lane]);
            }
        }
    }
    __builtin_nontemporal_store(acc, out + (size_t)node * HF + s * OUT_F + lane);
}

extern "C" void kernel_launch(void* const* d_in, const int* in_sizes, int n_in,
                              void* d_out, int out_size, void* d_ws, size_t ws_size,
                              hipStream_t stream) {
    const float* x      = (const float*)d_in[0];
    // d_in[1] = row_id, d_in[2] = row_ptr: implied by consistent CSR, unused.
    const int*   col_id = (const int*)d_in[3];
    const float* W      = (const float*)d_in[4];
    const float* atti   = (const float*)d_in[5];
    const float* attj   = (const float*)d_in[6];
    float* out = (float*)d_out;

    unsigned short* h = (unsigned short*)d_ws;                        // 25.6 MB
    float* a_i = (float*)((char*)d_ws + (size_t)N_NODES * HF * 2);    // 800 KB
    float* a_j = a_i + (size_t)N_NODES * HEADS;                       // 800 KB
    unsigned short* Wbp = (unsigned short*)(a_j + (size_t)N_NODES * HEADS); // 128 KB

    wprep<<<32, 256, 0, stream>>>(W, Wbp);
    proj_fused<<<(N_NODES + 31) / 32, 256, 0, stream>>>(x, Wbp, atti, attj, h, a_i, a_j);
    gat_agg2<<<N_NODES, 256, 0, stream>>>(h, a_i, a_j, col_id, out);
}

// Round 7
// 178.428 us; speedup vs baseline: 1.7275x; 1.7275x over previous
//
#include <hip/hip_runtime.h>
#include <hip/hip_bf16.h>
#include <stdint.h>

#define N_NODES 50000
#define DEG 16
#define IN_F 256
#define HEADS 4
#define OUT_F 64
#define HF 256          // HEADS * OUT_F
#define NEG_SLOPE 0.2f

typedef short bf16x8 __attribute__((ext_vector_type(8)));
typedef float f32x4 __attribute__((ext_vector_type(4)));

__device__ __forceinline__ unsigned short f2b(float f) {
    __hip_bfloat16 b = __float2bfloat16(f);
    return *(unsigned short*)&b;
}
__device__ __forceinline__ float b2f(unsigned short u) {
    union { uint32_t i; float f; } v; v.i = ((uint32_t)u) << 16;
    return v.f;
}

// Kernel 0: pack W [256][256] fp32 into bf16 MFMA-fragment order.
// Chunk G = (cb*8 + kc8)*64 + lane holds W[cb*16+(lane&15)][kc8*32+(lane>>4)*8 .. +8]
// so proj's bfrag load is one fully-contiguous 1KB wave read.
__global__ __launch_bounds__(256) void wprep(
    const float* __restrict__ W, unsigned short* __restrict__ Wbp)
{
    const int G = blockIdx.x * 256 + threadIdx.x;   // 8192 chunks
    const int cb   = G >> 9;
    const int rem  = G & 511;
    const int kc8  = rem >> 6;
    const int lane = rem & 63;
    const int kg   = lane >> 4;
    const int ar   = lane & 15;
    const float* src = W + (size_t)(cb * 16 + ar) * IN_F + kc8 * 32 + kg * 8;
    float4 f0 = ((const float4*)src)[0];
    float4 f1 = ((const float4*)src)[1];
    bf16x8 v;
    v[0] = (short)f2b(f0.x); v[1] = (short)f2b(f0.y);
    v[2] = (short)f2b(f0.z); v[3] = (short)f2b(f0.w);
    v[4] = (short)f2b(f1.x); v[5] = (short)f2b(f1.y);
    v[6] = (short)f2b(f1.z); v[7] = (short)f2b(f1.w);
    *(bf16x8*)(Wbp + (size_t)G * 8) = v;
}

// Kernel 1: fused projection GEMM + attention-half reduction.
// Tile 32 rows x 256 cols, 4 waves (wave = head, 64 cols), grid 1563 blocks.
__global__ __launch_bounds__(256) void proj_fused(
    const float* __restrict__ x, const unsigned short* __restrict__ Wbp,
    const float* __restrict__ atti, const float* __restrict__ attj,
    unsigned short* __restrict__ h,
    float* __restrict__ a_i, float* __restrict__ a_j)
{
    __shared__ unsigned short As[32 * 256];   // 16 KB

    const int tid  = threadIdx.x;
    const int lane = tid & 63;
    const int wave = tid >> 6;
    const int m0   = blockIdx.x * 32;

    // stage x-tile: 1024 16B-chunks, 4 per thread, coalesced fp32 reads
    #pragma unroll
    for (int p = 0; p < 4; p++) {
        const int C   = p * 256 + tid;
        const int row = C >> 5;
        const int c   = C & 31;
        int grow = m0 + row;
        if (grow >= N_NODES) grow = N_NODES - 1;
        const float* src = x + (size_t)grow * IN_F + c * 8;
        float4 f0 = ((const float4*)src)[0];
        float4 f1 = ((const float4*)src)[1];
        bf16x8 v;
        v[0] = (short)f2b(f0.x); v[1] = (short)f2b(f0.y);
        v[2] = (short)f2b(f0.z); v[3] = (short)f2b(f0.w);
        v[4] = (short)f2b(f1.x); v[5] = (short)f2b(f1.y);
        v[6] = (short)f2b(f1.z); v[7] = (short)f2b(f1.w);
        const int sc = c ^ (row & 7);
        *(bf16x8*)(As + row * 256 + sc * 8) = v;
    }
    __syncthreads();

    const int ar = lane & 15;
    const int kg = lane >> 4;
    const int ncol0 = wave * 64;

    f32x4 acc[2][4];
    #pragma unroll
    for (int i = 0; i < 2; i++)
        #pragma unroll
        for (int j = 0; j < 4; j++)
            #pragma unroll
            for (int k = 0; k < 4; k++) acc[i][j][k] = 0.0f;

    #pragma unroll
    for (int kc8 = 0; kc8 < 8; kc8++) {
        bf16x8 afrag[2], bfrag[4];
        #pragma unroll
        for (int mi = 0; mi < 2; mi++) {
            const int row = mi * 16 + ar;
            const int sc  = (kc8 * 4 + kg) ^ (row & 7);
            afrag[mi] = *(const bf16x8*)(As + row * 256 + sc * 8);
        }
        #pragma unroll
        for (int ni = 0; ni < 4; ni++) {
            const int cb = wave * 4 + ni;
            bfrag[ni] = *(const bf16x8*)(Wbp + ((size_t)(cb * 8 + kc8) * 64 + lane) * 8);
        }
        #pragma unroll
        for (int mi = 0; mi < 2; mi++)
            #pragma unroll
            for (int ni = 0; ni < 4; ni++)
                acc[mi][ni] = __builtin_amdgcn_mfma_f32_16x16x32_bf16(
                    afrag[mi], bfrag[ni], acc[mi][ni], 0, 0, 0);
    }

    // epilogue: h store (bf16) + fused a_i/a_j (fp32-acc precision)
    float ai_l[4], aj_l[4];
    #pragma unroll
    for (int ni = 0; ni < 4; ni++) {
        ai_l[ni] = atti[ncol0 + ni * 16 + ar];
        aj_l[ni] = attj[ncol0 + ni * 16 + ar];
    }
    #pragma unroll
    for (int mi = 0; mi < 2; mi++) {
        #pragma unroll
        for (int reg = 0; reg < 4; reg++) {
            const int row = m0 + mi * 16 + kg * 4 + reg;
            float pi = 0.f, pj = 0.f;
            #pragma unroll
            for (int ni = 0; ni < 4; ni++) {
                const float v = acc[mi][ni][reg];
                pi += v * ai_l[ni];
                pj += v * aj_l[ni];
            }
            #pragma unroll
            for (int off = 1; off < 16; off <<= 1) {
                pi += __shfl_xor(pi, off);
                pj += __shfl_xor(pj, off);
            }
            if (row < N_NODES) {
                #pragma unroll
                for (int ni = 0; ni < 4; ni++)
                    h[(size_t)row * HF + ncol0 + ni * 16 + ar] = f2b(acc[mi][ni][reg]);
                if (ar == 0) {
                    a_i[row * HEADS + wave] = pi;
                    a_j[row * HEADS + wave] = pj;
                }
            }
        }
    }
}

// Kernel 2: per-node softmax over 16 edges + weighted gather-sum.
// One wave per node; lane = (head = l>>4, edge j = l&15) for attention,
// output elements [4l, 4l+4) for aggregation. All 16 gathers batched in
// registers before accumulation (one vmcnt region, 16 loads in flight).
__global__ __launch_bounds__(256) void gat_agg(
    const unsigned short* __restrict__ h,
    const float* __restrict__ a_i, const float* __restrict__ a_j,
    const int* __restrict__ col, float* __restrict__ out)
{
    const int lane = threadIdx.x & 63;
    const int node = blockIdx.x * 4 + (threadIdx.x >> 6);
    if (node >= N_NODES) return;
    const int head = lane >> 4;
    const int j = lane & 15;

    const int src = col[node * DEG + j];
    float e = a_i[node * HEADS + head] + a_j[src * HEADS + head];
    e = (e > 0.0f) ? e : NEG_SLOPE * e;
    float m = e;
    #pragma unroll
    for (int off = 1; off < 16; off <<= 1) m = fmaxf(m, __shfl_xor(m, off));
    float p = __expf(e - m);
    float s = p;
    #pragma unroll
    for (int off = 1; off < 16; off <<= 1) s += __shfl_xor(s, off);
    const float alpha = p / (s + 1e-16f);

    // hoist all cross-lane reads first
    int   sj[DEG];
    float al[DEG];
    #pragma unroll
    for (int jj = 0; jj < DEG; jj++) {
        sj[jj] = __shfl(src, jj);
        al[jj] = __shfl(alpha, (lane & 48) + jj);
    }

    // batch-issue all 16 gathers (8B/lane, 512B/wave contiguous)
    const int myoff = lane * 4;
    ushort4 hv[DEG];
    #pragma unroll
    for (int jj = 0; jj < DEG; jj++)
        hv[jj] = *(const ushort4*)(h + (size_t)sj[jj] * HF + myoff);

    float acc0 = 0.f, acc1 = 0.f, acc2 = 0.f, acc3 = 0.f;
    #pragma unroll
    for (int jj = 0; jj < DEG; jj++) {
        acc0 += al[jj] * b2f(hv[jj].x);
        acc1 += al[jj] * b2f(hv[jj].y);
        acc2 += al[jj] * b2f(hv[jj].z);
        acc3 += al[jj] * b2f(hv[jj].w);
    }
    f32x4 o;
    o[0] = acc0; o[1] = acc1; o[2] = acc2; o[3] = acc3;
    __builtin_nontemporal_store(o, (f32x4*)(out + (size_t)node * HF + myoff));
}

extern "C" void kernel_launch(void* const* d_in, const int* in_sizes, int n_in,
                              void* d_out, int out_size, void* d_ws, size_t ws_size,
                              hipStream_t stream) {
    const float* x      = (const float*)d_in[0];
    // d_in[1] = row_id, d_in[2] = row_ptr: implied by consistent CSR, unused.
    const int*   col_id = (const int*)d_in[3];
    const float* W      = (const float*)d_in[4];
    const float* atti   = (const float*)d_in[5];
    const float* attj   = (const float*)d_in[6];
    float* out = (float*)d_out;

    unsigned short* h = (unsigned short*)d_ws;                        // 25.6 MB
    float* a_i = (float*)((char*)d_ws + (size_t)N_NODES * HF * 2);    // 800 KB
    float* a_j = a_i + (size_t)N_NODES * HEADS;                       // 800 KB
    unsigned short* Wbp = (unsigned short*)(a_j + (size_t)N_NODES * HEADS); // 128 KB

    wprep<<<32, 256, 0, stream>>>(W, Wbp);
    proj_fused<<<(N_NODES + 31) / 32, 256, 0, stream>>>(x, Wbp, atti, attj, h, a_i, a_j);
    gat_agg<<<(N_NODES + 3) / 4, 256, 0, stream>>>(h, a_i, a_j, col_id, out);
}